// Round 7
// baseline (113.355 us; speedup 1.0000x reference)
//
#include <hip/hip_runtime.h>
#include <hip/hip_fp16.h>

#define N_NODES 100000
#define N_EDGES 1000000
#define HIDDEN 64

// ---- geometry ----
#define N_RANGES 3
#define C_RANGE 33344                    // 3*33344 = 100,032 >= 100,000; bins 133,376 B LDS
#define N_SLICES 85                      // bin grid: 3*85 = 255 blocks -> 1 block/CU
#define PAIRS (N_EDGES / 2)              // 500,000 edge pairs
#define A_THREADS 1024

// partition geometry: 255 blocks, per-block segment per range, worst-case sized
#define NSEG_P 255
#define P_THREADS 1024
#define PPB_P ((PAIRS + NSEG_P - 1) / NSEG_P)    // 1961 pairs per partition block
#define SEG_CAP 7936                              // >= 4*PPB_P = 7844 (hard bound)

// kc[0..3]=(W1@Wout)[k], kc[4]=b1.Wout, kc[5..8]=W1[k][0], kc[9..12]=W1[k][1],
// kc[13]=b1[0], kc[14]=b1[1], kc[15]=Wout[0], kc[16]=Wout[1], kc[17]=bout[0]
__device__ __forceinline__ void compute_consts(
    const float* __restrict__ W1, const float* __restrict__ b1,
    const float* __restrict__ Wout, const float* __restrict__ bout,
    float* kc, int tid) {
    if (tid < 64) {
        float wj = Wout[tid];
        float p0 = W1[0 * HIDDEN + tid] * wj;
        float p1 = W1[1 * HIDDEN + tid] * wj;
        float p2 = W1[2 * HIDDEN + tid] * wj;
        float p3 = W1[3 * HIDDEN + tid] * wj;
        float pb = b1[tid] * wj;
        #pragma unroll
        for (int off = 32; off > 0; off >>= 1) {
            p0 += __shfl_down(p0, off);
            p1 += __shfl_down(p1, off);
            p2 += __shfl_down(p2, off);
            p3 += __shfl_down(p3, off);
            pb += __shfl_down(pb, off);
        }
        if (tid < 4) {
            kc[5 + tid] = W1[tid * HIDDEN + 0];
            kc[9 + tid] = W1[tid * HIDDEN + 1];
        }
        if (tid == 0) {
            kc[0] = p0; kc[1] = p1; kc[2] = p2; kc[3] = p3; kc[4] = pb;
            kc[13] = b1[0]; kc[14] = b1[1];
            kc[15] = Wout[0]; kc[16] = Wout[1];
            kc[17] = bout[0];
        }
    }
}

__device__ __forceinline__ float contrib(
    float4 xe, float cs, float sn_signed,
    float c0, float c1, float c2, float c3, float cb,
    float a0, float a1, float a2, float a3,
    float g0, float g1, float g2, float g3,
    float b10, float b11, float w0, float w1) {
    float h0 = xe.x * a0 + xe.y * a1 + xe.z * a2 + xe.w * a3 + b10;
    float h1 = xe.x * g0 + xe.y * g1 + xe.z * g2 + xe.w * g3 + b11;
    float d  = xe.x * c0 + xe.y * c1 + xe.z * c2 + xe.w * c3 + cb;
    float a  = h0 * w0 + h1 * w1;
    float b  = h0 * w1 - h1 * w0;
    return cs * a + sn_signed * b + (d - a);
}

__device__ __forceinline__ unsigned pack_half2(float x, float y) {
    __half2 h = __floats2half2_rn(x, y);
    return *(unsigned*)&h;
}

// ---- Kernel P (once): compute 4 contribs/pair, compact by dest range into
// per-(range, block) segments. No global atomics; 1 leader LDS atomic per
// (wave, range, slot). Entries: {dest_local, fp32 t} = 8 B.
__global__ __launch_bounds__(P_THREADS) void partition_kernel(
    const int4* __restrict__ epairs, const float2* __restrict__ ppairs,
    const float4* __restrict__ x4,
    const float* __restrict__ W1, const float* __restrict__ b1,
    const float* __restrict__ Wout, const float* __restrict__ bout,
    uint2* __restrict__ bucket, unsigned* __restrict__ counts) {
    __shared__ float kc[18];
    __shared__ unsigned blk_cnt[N_RANGES];
    const int tid = threadIdx.x;
    const int lane = tid & 63;

    compute_consts(W1, b1, Wout, bout, kc, tid);
    if (tid < N_RANGES) blk_cnt[tid] = 0;
    __syncthreads();

    const float c0 = kc[0], c1 = kc[1], c2 = kc[2], c3 = kc[3], cb = kc[4];
    const float a0 = kc[5], a1 = kc[6], a2 = kc[7], a3 = kc[8];
    const float g0 = kc[9], g1 = kc[10], g2 = kc[11], g3 = kc[12];
    const float b10 = kc[13], b11 = kc[14], w0 = kc[15], w1 = kc[16];

    const int pA = blockIdx.x * PPB_P;
    const int pB = min(pA + PPB_P, PAIRS);

    auto scatter = [&](int dest, float t, bool valid) {
        unsigned rr = valid ? ((unsigned)dest) / (unsigned)C_RANGE : 3u;
        unsigned lo = (unsigned)dest - rr * (unsigned)C_RANGE;
        #pragma unroll
        for (unsigned r = 0; r < N_RANGES; ++r) {
            unsigned long long mask = __ballot(rr == r);
            if (mask) {                               // wave-uniform branch
                int leader = __ffsll((long long)mask) - 1;
                unsigned base = 0;
                if (lane == leader)
                    base = atomicAdd(&blk_cnt[r], (unsigned)__popcll(mask));
                base = __shfl(base, leader);
                if (rr == r) {
                    unsigned ofs = (unsigned)__popcll(mask & ((1ull << lane) - 1));
                    bucket[(size_t)(r * NSEG_P + blockIdx.x) * SEG_CAP + base + ofs]
                        = make_uint2(lo, __float_as_uint(t));
                }
            }
        }
    };

    #pragma unroll
    for (int k = 0; k < (PPB_P + P_THREADS - 1) / P_THREADS; ++k) {   // 2, uniform
        int p = pA + tid + k * P_THREADS;
        bool valid = p < pB;
        int pc = valid ? p : 0;
        int4   ee = epairs[pc];                // edge0=(x,y), edge1=(z,w)
        float2 pp = ppairs[pc];

        float4 xu0 = x4[ee.x];
        float4 xv0 = x4[ee.y];
        float4 xu1 = x4[ee.z];
        float4 xv1 = x4[ee.w];

        float sn0, cs0, sn1, cs1;
        __sincosf(pp.x, &sn0, &cs0);
        __sincosf(pp.y, &sn1, &cs1);

        // tv* -> dest v (=ee.y/ee.w), from src u; tu* -> dest u (=ee.x/ee.z), from src v
        float tv0 = contrib(xu0, cs0,  sn0, c0,c1,c2,c3,cb, a0,a1,a2,a3, g0,g1,g2,g3, b10,b11,w0,w1);
        float tu0 = contrib(xv0, cs0, -sn0, c0,c1,c2,c3,cb, a0,a1,a2,a3, g0,g1,g2,g3, b10,b11,w0,w1);
        float tv1 = contrib(xu1, cs1,  sn1, c0,c1,c2,c3,cb, a0,a1,a2,a3, g0,g1,g2,g3, b10,b11,w0,w1);
        float tu1 = contrib(xv1, cs1, -sn1, c0,c1,c2,c3,cb, a0,a1,a2,a3, g0,g1,g2,g3, b10,b11,w0,w1);

        scatter(ee.y, tv0, valid);
        scatter(ee.x, tu0, valid);
        scatter(ee.w, tv1, valid);
        scatter(ee.z, tu1, valid);
    }
    __syncthreads();
    if (tid < N_RANGES) counts[tid * NSEG_P + blockIdx.x] = blk_cnt[tid];
}

// ---- Kernel A (once): dense binning. Every ds_add has ~all lanes active. ----
__global__ __launch_bounds__(A_THREADS) void bin_kernel(
    const uint2* __restrict__ bucket, const unsigned* __restrict__ counts,
    __half* __restrict__ part) {
    __shared__ __align__(16) float bins[C_RANGE];   // 133,376 B
    const int tid = threadIdx.x;
    const int r = blockIdx.x / N_SLICES;
    const int s = blockIdx.x - r * N_SLICES;

    {   // vectorized zero
        float4 z = make_float4(0.f, 0.f, 0.f, 0.f);
        float4* b4 = (float4*)bins;
        for (int j = tid; j < C_RANGE / 4; j += A_THREADS) b4[j] = z;
    }
    __syncthreads();

    // this block consumes segments s, s+85, s+170 of range r (~2614 entries each)
    for (int seg = s; seg < NSEG_P; seg += N_SLICES) {
        unsigned cnt = counts[r * NSEG_P + seg];
        const uint2* __restrict__ e = bucket + (size_t)(r * NSEG_P + seg) * SEG_CAP;
        for (unsigned j = tid; j < cnt; j += A_THREADS) {
            uint2 v = e[j];
            atomicAdd(&bins[v.x], __uint_as_float(v.y));
        }
    }
    __syncthreads();

    // fp16 flush: 4 bins -> uint2 (8 B) per thread-iter, coalesced
    uint2* __restrict__ d2 = (uint2*)(part + (size_t)blockIdx.x * C_RANGE);
    const float4* b4 = (const float4*)bins;
    for (int j = tid; j < C_RANGE / 4; j += A_THREADS) {
        float4 v = b4[j];
        d2[j] = make_uint2(pack_half2(v.x, v.y), pack_half2(v.z, v.w));
    }
}

// ---- Kernel B: 2 nodes/thread (r2-proven); out = partial sums + direct term ----
__global__ __launch_bounds__(512) void reduce_kernel(
    const float4* __restrict__ x4,
    const float* __restrict__ W1, const float* __restrict__ b1,
    const float* __restrict__ Wout, const float* __restrict__ bout,
    const __half2* __restrict__ part2, float2* __restrict__ out2) {
    __shared__ float kc[18];
    compute_consts(W1, b1, Wout, bout, kc, threadIdx.x);
    __syncthreads();
    int t = blockIdx.x * 512 + threadIdx.x;
    int i0 = t * 2;
    if (i0 >= N_NODES) return;
    int r = i0 / C_RANGE;                // compile-time magic-mul; i0,i0+1 same range
    int j = i0 - r * C_RANGE;            // even -> half2-aligned
    const __half2* __restrict__ p = part2
        + (size_t)(r * N_SLICES) * (C_RANGE / 2) + (j >> 1);
    float s0 = 0.0f, s1 = 0.0f;
    #pragma unroll 5
    for (int s = 0; s < N_SLICES; s++) {
        float2 v = __half22float2(p[(size_t)s * (C_RANGE / 2)]);
        s0 += v.x; s1 += v.y;
    }
    float4 xa = x4[i0];
    float4 xb = x4[i0 + 1];
    float base = kc[4] + kc[17];
    out2[t] = make_float2(
        s0 + xa.x * kc[0] + xa.y * kc[1] + xa.z * kc[2] + xa.w * kc[3] + base,
        s1 + xb.x * kc[0] + xb.y * kc[1] + xb.z * kc[2] + xb.w * kc[3] + base);
}

// ---- Fallback (ws too small): direct device atomics ----------------------
__global__ void precompute_kernel(const float* __restrict__ W1,
                                  const float* __restrict__ b1,
                                  const float* __restrict__ Wout,
                                  const float* __restrict__ bout,
                                  float* __restrict__ consts) {
    __shared__ float kc[18];
    compute_consts(W1, b1, Wout, bout, kc, threadIdx.x);
    __syncthreads();
    if (threadIdx.x < 18) consts[threadIdx.x] = kc[threadIdx.x];
}

__global__ void edge_atomic_kernel(const int2* __restrict__ edges,
                                   const float* __restrict__ phases,
                                   const float4* __restrict__ x4,
                                   const float* __restrict__ consts,
                                   float* __restrict__ rep) {
    int e = blockIdx.x * blockDim.x + threadIdx.x;
    if (e >= N_EDGES) return;
    float c0 = consts[0], c1 = consts[1], c2 = consts[2], c3 = consts[3];
    float cb = consts[4];
    float a0 = consts[5], a1 = consts[6], a2 = consts[7], a3 = consts[8];
    float g0 = consts[9], g1 = consts[10], g2 = consts[11], g3 = consts[12];
    float b10 = consts[13], b11 = consts[14], w0 = consts[15], w1 = consts[16];
    int2 ed = edges[e];
    float ph = phases[e];
    float sn, cs;
    __sincosf(ph, &sn, &cs);
    float4 xu = x4[ed.x];
    float4 xv = x4[ed.y];
    atomicAdd(rep + ed.y, contrib(xu, cs,  sn, c0,c1,c2,c3,cb, a0,a1,a2,a3, g0,g1,g2,g3, b10,b11,w0,w1));
    atomicAdd(rep + ed.x, contrib(xv, cs, -sn, c0,c1,c2,c3,cb, a0,a1,a2,a3, g0,g1,g2,g3, b10,b11,w0,w1));
}

__global__ void final_kernel(const float4* __restrict__ x4,
                             const float* __restrict__ consts,
                             const float* __restrict__ rep,
                             float* __restrict__ out) {
    int i = blockIdx.x * blockDim.x + threadIdx.x;
    if (i >= N_NODES) return;
    float4 xi = x4[i];
    out[i] = rep[i] + xi.x * consts[0] + xi.y * consts[1] + xi.z * consts[2]
           + xi.w * consts[3] + consts[4] + consts[17];
}

extern "C" void kernel_launch(void* const* d_in, const int* in_sizes, int n_in,
                              void* d_out, int out_size, void* d_ws, size_t ws_size,
                              hipStream_t stream) {
    const float* x      = (const float*)d_in[0];
    const int*   edges  = (const int*)d_in[1];
    const float* W1     = (const float*)d_in[2];
    const float* b1     = (const float*)d_in[3];
    const float* phases = (const float*)d_in[4];
    const float* Wout   = (const float*)d_in[5];
    const float* bout   = (const float*)d_in[6];
    float* out = (float*)d_out;

    const size_t part_bytes =
        (size_t)N_RANGES * N_SLICES * C_RANGE * sizeof(__half);       // 17,005,440 B
    const size_t bucket_off   = part_bytes;                            // 16B-mult
    const size_t bucket_bytes =
        (size_t)N_RANGES * NSEG_P * SEG_CAP * sizeof(uint2);           // 48,568,320 B
    const size_t counts_off   = bucket_off + bucket_bytes;
    const size_t counts_bytes = (size_t)N_RANGES * NSEG_P * sizeof(unsigned);
    const size_t need         = counts_off + counts_bytes;             // ~65.6 MB

    if (ws_size >= need) {
        __half*   part   = (__half*)d_ws;
        uint2*    bucket = (uint2*)((char*)d_ws + bucket_off);
        unsigned* counts = (unsigned*)((char*)d_ws + counts_off);
        // No memsets: every counts slot is written by its partition block,
        // bucket is read only in [0, cnt), part written by exactly one block.
        partition_kernel<<<NSEG_P, P_THREADS, 0, stream>>>(
            (const int4*)edges, (const float2*)phases, (const float4*)x,
            W1, b1, Wout, bout, bucket, counts);
        bin_kernel<<<N_RANGES * N_SLICES, A_THREADS, 0, stream>>>(
            bucket, counts, part);
        reduce_kernel<<<(N_NODES / 2 + 511) / 512, 512, 0, stream>>>(
            (const float4*)x, W1, b1, Wout, bout,
            (const __half2*)part, (float2*)out);
    } else {
        float* consts = (float*)d_ws;
        float* rep    = (float*)((char*)d_ws + 256);
        hipMemsetAsync(rep, 0, N_NODES * sizeof(float), stream);
        precompute_kernel<<<1, 64, 0, stream>>>(W1, b1, Wout, bout, consts);
        edge_atomic_kernel<<<(N_EDGES + 255) / 256, 256, 0, stream>>>(
            (const int2*)edges, phases, (const float4*)x, consts, rep);
        final_kernel<<<(N_NODES + 255) / 256, 256, 0, stream>>>(
            (const float4*)x, consts, rep, out);
    }
}

// Round 8
// 99.520 us; speedup vs baseline: 1.1390x; 1.1390x over previous
//
#include <hip/hip_runtime.h>
#include <hip/hip_fp16.h>

#define N_NODES 100000
#define N_EDGES 1000000
#define HIDDEN 64

// ---- range-pass geometry (r0-proven: 3 ranges, fp32 LDS bins, 2 dispatches) ----
#define N_RANGES 3
#define C_RANGE 33344                    // 3*33344 = 100,032 >= 100,000; bins 133,376 B LDS
#define N_SLICES 85                      // 3*85 = 255 blocks -> exactly 1 block/CU
#define PAIRS (N_EDGES / 2)              // 500,000 edge pairs
#define PPB ((PAIRS + N_SLICES - 1) / N_SLICES)   // 5883 pairs per slice
#define A_THREADS 1024                   // 16 waves in the single resident block
#define R_THREADS 256                    // reduce: 196 blocks spread over 256 CUs

// kc[0..3]=(W1@Wout)[k], kc[4]=b1.Wout, kc[5..8]=W1[k][0], kc[9..12]=W1[k][1],
// kc[13]=b1[0], kc[14]=b1[1], kc[15]=Wout[0], kc[16]=Wout[1], kc[17]=bout[0]
__device__ __forceinline__ void compute_consts(
    const float* __restrict__ W1, const float* __restrict__ b1,
    const float* __restrict__ Wout, const float* __restrict__ bout,
    float* kc, int tid) {
    if (tid < 64) {
        float wj = Wout[tid];
        float p0 = W1[0 * HIDDEN + tid] * wj;
        float p1 = W1[1 * HIDDEN + tid] * wj;
        float p2 = W1[2 * HIDDEN + tid] * wj;
        float p3 = W1[3 * HIDDEN + tid] * wj;
        float pb = b1[tid] * wj;
        #pragma unroll
        for (int off = 32; off > 0; off >>= 1) {
            p0 += __shfl_down(p0, off);
            p1 += __shfl_down(p1, off);
            p2 += __shfl_down(p2, off);
            p3 += __shfl_down(p3, off);
            pb += __shfl_down(pb, off);
        }
        if (tid < 4) {
            kc[5 + tid] = W1[tid * HIDDEN + 0];
            kc[9 + tid] = W1[tid * HIDDEN + 1];
        }
        if (tid == 0) {
            kc[0] = p0; kc[1] = p1; kc[2] = p2; kc[3] = p3; kc[4] = pb;
            kc[13] = b1[0]; kc[14] = b1[1];
            kc[15] = Wout[0]; kc[16] = Wout[1];
            kc[17] = bout[0];
        }
    }
}

__device__ __forceinline__ float contrib(
    float4 xe, float cs, float sn_signed,
    float c0, float c1, float c2, float c3, float cb,
    float a0, float a1, float a2, float a3,
    float g0, float g1, float g2, float g3,
    float b10, float b11, float w0, float w1) {
    float h0 = xe.x * a0 + xe.y * a1 + xe.z * a2 + xe.w * a3 + b10;
    float h1 = xe.x * g0 + xe.y * g1 + xe.z * g2 + xe.w * g3 + b11;
    float d  = xe.x * c0 + xe.y * c1 + xe.z * c2 + xe.w * c3 + cb;
    float a  = h0 * w0 + h1 * w1;
    float b  = h0 * w1 - h1 * w0;
    return cs * a + sn_signed * b + (d - a);
}

__device__ __forceinline__ unsigned pack_half2(float x, float y) {
    __half2 h = __floats2half2_rn(x, y);
    return *(unsigned*)&h;
}

// ---- Kernel A: r0's proven loop, verbatim structure ----
__global__ __launch_bounds__(A_THREADS) void range_kernel(
    const int4* __restrict__ epairs, const float2* __restrict__ ppairs,
    const float4* __restrict__ x4,
    const float* __restrict__ W1, const float* __restrict__ b1,
    const float* __restrict__ Wout, const float* __restrict__ bout,
    __half* __restrict__ part) {
    __shared__ __align__(16) float bins[C_RANGE];   // 133,376 B
    __shared__ float kc[18];
    const int tid = threadIdx.x;
    const int r = blockIdx.x / N_SLICES;
    const int s = blockIdx.x - r * N_SLICES;

    compute_consts(W1, b1, Wout, bout, kc, tid);
    {   // vectorized zero: C_RANGE/4 = 8336 float4 slots
        float4 z = make_float4(0.f, 0.f, 0.f, 0.f);
        float4* b4 = (float4*)bins;
        for (int j = tid; j < C_RANGE / 4; j += A_THREADS) b4[j] = z;
    }
    __syncthreads();

    const float c0 = kc[0], c1 = kc[1], c2 = kc[2], c3 = kc[3], cb = kc[4];
    const float a0 = kc[5], a1 = kc[6], a2 = kc[7], a3 = kc[8];
    const float g0 = kc[9], g1 = kc[10], g2 = kc[11], g3 = kc[12];
    const float b10 = kc[13], b11 = kc[14], w0 = kc[15], w1 = kc[16];

    const int nlo = r * C_RANGE;
    const int pA = s * PPB;
    const int pB = min(pA + PPB, PAIRS);

    #pragma unroll 2
    for (int p = pA + tid; p < pB; p += A_THREADS) {
        int4   ee = epairs[p];                 // edge0=(x,y), edge1=(z,w)
        float2 pp = ppairs[p];

        unsigned jv0 = (unsigned)(ee.y - nlo); // dest v0, src u0
        unsigned ju0 = (unsigned)(ee.x - nlo); // dest u0, src v0
        unsigned jv1 = (unsigned)(ee.w - nlo);
        unsigned ju1 = (unsigned)(ee.z - nlo);
        bool pv0 = jv0 < C_RANGE, pu0 = ju0 < C_RANGE;
        bool pv1 = jv1 < C_RANGE, pu1 = ju1 < C_RANGE;

        // clamped gathers — always issued, single basic block
        float4 xsv0 = x4[pv0 ? ee.x : 0];
        float4 xsu0 = x4[pu0 ? ee.y : 0];
        float4 xsv1 = x4[pv1 ? ee.z : 0];
        float4 xsu1 = x4[pu1 ? ee.w : 0];

        float sn0, cs0, sn1, cs1;
        __sincosf(pp.x, &sn0, &cs0);
        __sincosf(pp.y, &sn1, &cs1);

        float tv0 = contrib(xsv0, cs0,  sn0, c0,c1,c2,c3,cb, a0,a1,a2,a3, g0,g1,g2,g3, b10,b11,w0,w1);
        float tu0 = contrib(xsu0, cs0, -sn0, c0,c1,c2,c3,cb, a0,a1,a2,a3, g0,g1,g2,g3, b10,b11,w0,w1);
        float tv1 = contrib(xsv1, cs1,  sn1, c0,c1,c2,c3,cb, a0,a1,a2,a3, g0,g1,g2,g3, b10,b11,w0,w1);
        float tu1 = contrib(xsu1, cs1, -sn1, c0,c1,c2,c3,cb, a0,a1,a2,a3, g0,g1,g2,g3, b10,b11,w0,w1);

        if (pv0) atomicAdd(&bins[jv0], tv0);
        if (pu0) atomicAdd(&bins[ju0], tu0);
        if (pv1) atomicAdd(&bins[jv1], tv1);
        if (pu1) atomicAdd(&bins[ju1], tu1);
    }
    __syncthreads();

    // fp16 flush: 4 bins -> uint2 (8 B) per thread-iter, coalesced
    uint2* __restrict__ d2 = (uint2*)(part + (size_t)blockIdx.x * C_RANGE);
    const float4* b4 = (const float4*)bins;
    for (int j = tid; j < C_RANGE / 4; j += A_THREADS) {
        float4 v = b4[j];
        d2[j] = make_uint2(pack_half2(v.x, v.y), pack_half2(v.z, v.w));
    }
}

// ---- Kernel B: half2-paired reduce, 2 nodes/thread, 196 small blocks ----
__global__ __launch_bounds__(R_THREADS) void reduce_kernel(
    const float4* __restrict__ x4,
    const float* __restrict__ W1, const float* __restrict__ b1,
    const float* __restrict__ Wout, const float* __restrict__ bout,
    const __half2* __restrict__ part2, float2* __restrict__ out2) {
    __shared__ float kc[18];
    compute_consts(W1, b1, Wout, bout, kc, threadIdx.x);
    __syncthreads();
    int t = blockIdx.x * R_THREADS + threadIdx.x;
    int i0 = t * 2;
    if (i0 >= N_NODES) return;
    int r = i0 / C_RANGE;                // compile-time magic-mul; i0,i0+1 same range
    int j = i0 - r * C_RANGE;            // even -> half2-aligned
    const __half2* __restrict__ p = part2
        + (size_t)(r * N_SLICES) * (C_RANGE / 2) + (j >> 1);
    float s0 = 0.0f, s1 = 0.0f;
    #pragma unroll 5
    for (int s = 0; s < N_SLICES; s++) {
        float2 v = __half22float2(p[(size_t)s * (C_RANGE / 2)]);
        s0 += v.x; s1 += v.y;
    }
    float4 xa = x4[i0];
    float4 xb = x4[i0 + 1];
    float base = kc[4] + kc[17];
    out2[t] = make_float2(
        s0 + xa.x * kc[0] + xa.y * kc[1] + xa.z * kc[2] + xa.w * kc[3] + base,
        s1 + xb.x * kc[0] + xb.y * kc[1] + xb.z * kc[2] + xb.w * kc[3] + base);
}

// ---- Fallback (ws too small): direct device atomics ----------------------
__global__ void precompute_kernel(const float* __restrict__ W1,
                                  const float* __restrict__ b1,
                                  const float* __restrict__ Wout,
                                  const float* __restrict__ bout,
                                  float* __restrict__ consts) {
    __shared__ float kc[18];
    compute_consts(W1, b1, Wout, bout, kc, threadIdx.x);
    __syncthreads();
    if (threadIdx.x < 18) consts[threadIdx.x] = kc[threadIdx.x];
}

__global__ void edge_atomic_kernel(const int2* __restrict__ edges,
                                   const float* __restrict__ phases,
                                   const float4* __restrict__ x4,
                                   const float* __restrict__ consts,
                                   float* __restrict__ rep) {
    int e = blockIdx.x * blockDim.x + threadIdx.x;
    if (e >= N_EDGES) return;
    float c0 = consts[0], c1 = consts[1], c2 = consts[2], c3 = consts[3];
    float cb = consts[4];
    float a0 = consts[5], a1 = consts[6], a2 = consts[7], a3 = consts[8];
    float g0 = consts[9], g1 = consts[10], g2 = consts[11], g3 = consts[12];
    float b10 = consts[13], b11 = consts[14], w0 = consts[15], w1 = consts[16];
    int2 ed = edges[e];
    float ph = phases[e];
    float sn, cs;
    __sincosf(ph, &sn, &cs);
    float4 xu = x4[ed.x];
    float4 xv = x4[ed.y];
    atomicAdd(rep + ed.y, contrib(xu, cs,  sn, c0,c1,c2,c3,cb, a0,a1,a2,a3, g0,g1,g2,g3, b10,b11,w0,w1));
    atomicAdd(rep + ed.x, contrib(xv, cs, -sn, c0,c1,c2,c3,cb, a0,a1,a2,a3, g0,g1,g2,g3, b10,b11,w0,w1));
}

__global__ void final_kernel(const float4* __restrict__ x4,
                             const float* __restrict__ consts,
                             const float* __restrict__ rep,
                             float* __restrict__ out) {
    int i = blockIdx.x * blockDim.x + threadIdx.x;
    if (i >= N_NODES) return;
    float4 xi = x4[i];
    out[i] = rep[i] + xi.x * consts[0] + xi.y * consts[1] + xi.z * consts[2]
           + xi.w * consts[3] + consts[4] + consts[17];
}

extern "C" void kernel_launch(void* const* d_in, const int* in_sizes, int n_in,
                              void* d_out, int out_size, void* d_ws, size_t ws_size,
                              hipStream_t stream) {
    const float* x      = (const float*)d_in[0];
    const int*   edges  = (const int*)d_in[1];
    const float* W1     = (const float*)d_in[2];
    const float* b1     = (const float*)d_in[3];
    const float* phases = (const float*)d_in[4];
    const float* Wout   = (const float*)d_in[5];
    const float* bout   = (const float*)d_in[6];
    float* out = (float*)d_out;

    const size_t part_bytes =
        (size_t)N_RANGES * N_SLICES * C_RANGE * sizeof(__half);   // 17,005,440 B

    if (ws_size >= part_bytes) {
        __half* part = (__half*)d_ws;
        // No memset needed: every part slot is written by exactly one block.
        range_kernel<<<N_RANGES * N_SLICES, A_THREADS, 0, stream>>>(
            (const int4*)edges, (const float2*)phases, (const float4*)x,
            W1, b1, Wout, bout, part);
        reduce_kernel<<<(N_NODES / 2 + R_THREADS - 1) / R_THREADS, R_THREADS, 0, stream>>>(
            (const float4*)x, W1, b1, Wout, bout,
            (const __half2*)part, (float2*)out);
    } else {
        float* consts = (float*)d_ws;
        float* rep    = (float*)((char*)d_ws + 256);
        hipMemsetAsync(rep, 0, N_NODES * sizeof(float), stream);
        precompute_kernel<<<1, 64, 0, stream>>>(W1, b1, Wout, bout, consts);
        edge_atomic_kernel<<<(N_EDGES + 255) / 256, 256, 0, stream>>>(
            (const int2*)edges, phases, (const float4*)x, consts, rep);
        final_kernel<<<(N_NODES + 255) / 256, 256, 0, stream>>>(
            (const float4*)x, consts, rep, out);
    }
}